// Round 1
// baseline (40.878 us; speedup 1.0000x reference)
//
#include <hip/hip_runtime.h>

// HEAT layer, exploiting sorted timestamps:
// out[i,d] = P[cnt_i][d] + eps*exp(beta*t_i) * Q[cnt_i][d]
//   P[k][d] = sum_{j<k} h[j][d]
//   Q[k][d] = sum_{j<k} relu(h[j][d]) * exp(-beta*t_j)
//   cnt_i   = upper_bound(t, t[i])   (handles duplicate timestamps exactly)

namespace {
constexpr int S  = 8192;
constexpr int D  = 768;
constexpr int CH = 32;          // rows per chunk
constexpr int NC = S / CH;      // 256 chunks
constexpr int TILE = 256;       // columns per block
constexpr int NTILES = D / TILE; // 3
constexpr int UB = 8;           // load batch depth (loads in flight per wave)
}

__global__ __launch_bounds__(256)
void heat_setup(const float* __restrict__ t,
                const float* __restrict__ eps_p,
                const float* __restrict__ beta_p,
                int* __restrict__ cnt,
                float* __restrict__ epos,
                float* __restrict__ decay) {
    int i = blockIdx.x * blockDim.x + threadIdx.x;
    if (i >= S) return;
    float eps = eps_p[0];
    float beta = beta_p[0];
    float ti = t[i];
    // upper_bound over sorted t
    int lo = 0, hi = S;
    while (lo < hi) {
        int mid = (lo + hi) >> 1;
        if (t[mid] <= ti) lo = mid + 1; else hi = mid;
    }
    cnt[i]   = lo;
    epos[i]  = eps * expf(beta * ti);
    decay[i] = expf(-beta * ti);
}

__global__ __launch_bounds__(TILE)
void heat_partials(const float* __restrict__ h,
                   const float* __restrict__ decay,
                   float* __restrict__ SP,
                   float* __restrict__ SQ) {
    const int c = blockIdx.x;
    const int d = blockIdx.y * TILE + threadIdx.x;
    const float* hp = h + (size_t)c * CH * D + d;
    const int j0 = c * CH;
    float p = 0.f, q = 0.f;
    for (int rb = 0; rb < CH; rb += UB) {
        float hv[UB];
#pragma unroll
        for (int u = 0; u < UB; ++u) hv[u] = hp[(size_t)(rb + u) * D];
#pragma unroll
        for (int u = 0; u < UB; ++u) {
            p += hv[u];
            q += fmaxf(hv[u], 0.f) * decay[j0 + rb + u];
        }
    }
    SP[c * D + d] = p;
    SQ[c * D + d] = q;
}

__global__ __launch_bounds__(256)
void heat_scan(const float* __restrict__ SP,
               const float* __restrict__ SQ,
               float* __restrict__ offP,
               float* __restrict__ offQ) {
    const int d = blockIdx.x * blockDim.x + threadIdx.x; // 0..D-1
    float rp = 0.f, rq = 0.f;
    constexpr int CB = 16;
    for (int cb = 0; cb < NC; cb += CB) {
        float sp[CB], sq[CB];
#pragma unroll
        for (int u = 0; u < CB; ++u) {
            sp[u] = SP[(cb + u) * D + d];
            sq[u] = SQ[(cb + u) * D + d];
        }
#pragma unroll
        for (int u = 0; u < CB; ++u) {
            offP[(cb + u) * D + d] = rp;
            offQ[(cb + u) * D + d] = rq;
            rp += sp[u];
            rq += sq[u];
        }
    }
}

__global__ __launch_bounds__(TILE)
void heat_out(const float* __restrict__ h,
              const int* __restrict__ cnt,
              const float* __restrict__ epos,
              const float* __restrict__ decay,
              const float* __restrict__ offP,
              const float* __restrict__ offQ,
              float* __restrict__ out) {
    const int c = blockIdx.x;
    const int d = blockIdx.y * TILE + threadIdx.x;
    float p = offP[c * D + d];
    float q = offQ[c * D + d];
    const int rowEnd = (c + 1) * CH;
    int ptr = c * CH;
    int j   = c * CH;

    // Main path: the chunk's CH rows, loads batched UB deep.
    for (int rb = 0; rb < CH; rb += UB) {
        float hv[UB];
#pragma unroll
        for (int u = 0; u < UB; ++u) hv[u] = h[(size_t)(j + u) * D + d];
#pragma unroll
        for (int u = 0; u < UB; ++u) {
            p += hv[u];
            q += fmaxf(hv[u], 0.f) * decay[j];
            ++j;
            while (ptr < rowEnd && cnt[ptr] == j) {
                out[(size_t)ptr * D + d] = p + epos[ptr] * q;
                ++ptr;
            }
        }
    }
    // Tail: duplicate-t runs crossing the chunk boundary (rare). Keep
    // accumulating rows beyond the chunk until all our rows are emitted.
    while (ptr < rowEnd) {
        float hv = h[(size_t)j * D + d];
        p += hv;
        q += fmaxf(hv, 0.f) * decay[j];
        ++j;
        while (ptr < rowEnd && cnt[ptr] == j) {
            out[(size_t)ptr * D + d] = p + epos[ptr] * q;
            ++ptr;
        }
    }
}

extern "C" void kernel_launch(void* const* d_in, const int* in_sizes, int n_in,
                              void* d_out, int out_size, void* d_ws, size_t ws_size,
                              hipStream_t stream) {
    const float* h    = (const float*)d_in[0];
    const float* t    = (const float*)d_in[1];
    const float* eps  = (const float*)d_in[2];
    const float* beta = (const float*)d_in[3];
    float* out = (float*)d_out;

    // ws carve-up (floats): cnt|epos|decay|SP|SQ|offP|offQ  (~3.1 MB)
    float* ws    = (float*)d_ws;
    int*   cnt   = (int*)ws;         // S ints
    float* epos  = ws + S;           // S
    float* decay = ws + 2 * S;       // S
    float* SP    = ws + 3 * S;       // NC*D
    float* SQ    = SP + NC * D;
    float* offP  = SQ + NC * D;
    float* offQ  = offP + NC * D;

    heat_setup<<<S / 256, 256, 0, stream>>>(t, eps, beta, cnt, epos, decay);
    heat_partials<<<dim3(NC, NTILES), TILE, 0, stream>>>(h, decay, SP, SQ);
    heat_scan<<<D / 256, 256, 0, stream>>>(SP, SQ, offP, offQ);
    heat_out<<<dim3(NC, NTILES), TILE, 0, stream>>>(h, cnt, epos, decay, offP, offQ, out);
}

// Round 3
// 21.461 us; speedup vs baseline: 1.9047x; 1.9047x over previous
//
#include <hip/hip_runtime.h>

// HEAT layer with sorted timestamps, 3 plain kernels (no grid sync):
//   out[i] = P_inc[i] + eps*exp(beta*t_i) * Q_inc[i]   (+ duplicate-t fixup)
//   P_inc[i] = sum_{j<=i} h[j],  Q_inc[i] = sum_{j<=i} relu(h[j])*exp(-beta*t_j)
// Rows j>i with t[j]==t[i] contribute h[j] + eps*relu(h[j]) exactly
// (exp(beta*0)=1) -> rare in-kernel forward fixup, no upper_bound/cnt pass.
//
// K1: per-chunk (32-row) partial sums SP/SQ        (reads h once)
// K2: exclusive scan of chunk sums -> offP/offQ    (24 blocks, 2-level)
// K3: re-read h, emit out from registers           (reads h + writes out)

namespace {
constexpr int S   = 8192;
constexpr int D   = 768;
constexpr int DV  = D / 4;       // 192 float4 per row
constexpr int CH  = 32;          // rows per chunk
constexpr int NC  = S / CH;      // 256 chunks
constexpr int QL  = 64;          // float4-columns per block
constexpr int NG  = DV / QL;     // 3 column groups
constexpr int RG  = 4;           // row-groups per chunk
constexpr int RR  = CH / RG;     // 8 rows per row-group
constexpr int SEG = 16;          // scan segments
constexpr int CPS = NC / SEG;    // 16 chunks per segment
constexpr int QPB = 16;          // quads per scan block
constexpr int SBP = DV / QPB;    // 12 scan blocks per array
}

__device__ __forceinline__ float4 f4add(float4 a, float4 b) {
    return make_float4(a.x + b.x, a.y + b.y, a.z + b.z, a.w + b.w);
}
__device__ __forceinline__ void f4relu_fma(float4& acc, float4 h, float d) {
    acc.x += fmaxf(h.x, 0.f) * d;
    acc.y += fmaxf(h.y, 0.f) * d;
    acc.z += fmaxf(h.z, 0.f) * d;
    acc.w += fmaxf(h.w, 0.f) * d;
}

__global__ __launch_bounds__(256)
void heat_partials(const float* __restrict__ h, const float* __restrict__ t,
                   const float* __restrict__ betap,
                   float4* __restrict__ SP, float4* __restrict__ SQ) {
    const int tid = threadIdx.x, lane = tid & (QL - 1), r = tid >> 6;
    const int c = blockIdx.x, g = blockIdx.y;
    const int q = g * QL + lane;
    __shared__ float dec[CH];
    __shared__ float4 rgP[RG][QL], rgQ[RG][QL];
    if (tid < CH) dec[tid] = expf(-betap[0] * t[c * CH + tid]);
    __syncthreads();
    const float4* h4 = (const float4*)h;
    const int row0 = c * CH + r * RR;
    float4 hv[RR];
#pragma unroll
    for (int k = 0; k < RR; ++k) hv[k] = h4[(size_t)(row0 + k) * DV + q];
    float4 pp = {0, 0, 0, 0}, qq = {0, 0, 0, 0};
#pragma unroll
    for (int k = 0; k < RR; ++k) {
        pp = f4add(pp, hv[k]);
        f4relu_fma(qq, hv[k], dec[r * RR + k]);
    }
    rgP[r][lane] = pp;
    rgQ[r][lane] = qq;
    __syncthreads();
    if (r == 0) {
        SP[c * DV + q] = f4add(f4add(rgP[0][lane], rgP[1][lane]),
                               f4add(rgP[2][lane], rgP[3][lane]));
        SQ[c * DV + q] = f4add(f4add(rgQ[0][lane], rgQ[1][lane]),
                               f4add(rgQ[2][lane], rgQ[3][lane]));
    }
}

__global__ __launch_bounds__(256)
void heat_scan(const float4* __restrict__ SP, const float4* __restrict__ SQ,
               float4* __restrict__ offP, float4* __restrict__ offQ) {
    const int blk = blockIdx.x;
    const bool isQ = blk >= SBP;
    const int lb = isQ ? blk - SBP : blk;
    const float4* src = isQ ? SQ : SP;
    float4*       dst = isQ ? offQ : offP;
    const int qk = threadIdx.x & (QPB - 1);
    const int sg = threadIdx.x >> 4;       // segment 0..15
    const int qs = lb * QPB + qk;          // column quad
    const int c0 = sg * CPS;
    __shared__ float4 ssum[SEG][QPB];
    float4 v[CPS];
#pragma unroll
    for (int u = 0; u < CPS; ++u) v[u] = src[(c0 + u) * DV + qs];
    float4 tot = {0, 0, 0, 0};
#pragma unroll
    for (int u = 0; u < CPS; ++u) tot = f4add(tot, v[u]);
    ssum[sg][qk] = tot;
    __syncthreads();
    float4 run = {0, 0, 0, 0};
    for (int s2 = 0; s2 < SEG - 1; ++s2)
        if (s2 < sg) run = f4add(run, ssum[s2][qk]);
#pragma unroll
    for (int u = 0; u < CPS; ++u) {
        dst[(c0 + u) * DV + qs] = run;
        run = f4add(run, v[u]);
    }
}

__global__ __launch_bounds__(256)
void heat_out(const float* __restrict__ h, const float* __restrict__ t,
              const float* __restrict__ epsp, const float* __restrict__ betap,
              const float4* __restrict__ offP, const float4* __restrict__ offQ,
              float* __restrict__ out) {
    const int tid = threadIdx.x, lane = tid & (QL - 1), r = tid >> 6;
    const int c = blockIdx.x, g = blockIdx.y;
    const int q = g * QL + lane;
    const float eps = epsp[0], beta = betap[0];
    __shared__ float tt[CH + 1];
    __shared__ float4 rgP[RG][QL], rgQ[RG][QL];
    if (tid <= CH) {
        int j = c * CH + tid;
        tt[tid] = (j < S) ? t[j] : 1e30f;   // sentinel past the end
    }
    __syncthreads();
    const float4* h4 = (const float4*)h;
    float4* out4 = (float4*)out;
    const int row0 = c * CH + r * RR;
    float4 hv[RR];
#pragma unroll
    for (int k = 0; k < RR; ++k) hv[k] = h4[(size_t)(row0 + k) * DV + q];
    float tv[RR], dc[RR];
#pragma unroll
    for (int k = 0; k < RR; ++k) {
        tv[k] = tt[r * RR + k];
        dc[k] = expf(-beta * tv[k]);
    }
    float4 pp = {0, 0, 0, 0}, qq = {0, 0, 0, 0};
#pragma unroll
    for (int k = 0; k < RR; ++k) {
        pp = f4add(pp, hv[k]);
        f4relu_fma(qq, hv[k], dc[k]);
    }
    rgP[r][lane] = pp;
    rgQ[r][lane] = qq;
    __syncthreads();
    float4 po = offP[c * DV + q];
    float4 qo = offQ[c * DV + q];
#pragma unroll
    for (int rr = 0; rr < RG - 1; ++rr)
        if (rr < r) {
            po = f4add(po, rgP[rr][lane]);
            qo = f4add(qo, rgQ[rr][lane]);
        }
#pragma unroll
    for (int k = 0; k < RR; ++k) {
        po = f4add(po, hv[k]);
        f4relu_fma(qo, hv[k], dc[k]);
        const float ep = eps * expf(beta * tv[k]);
        float4 o;
        o.x = po.x + ep * qo.x;
        o.y = po.y + ep * qo.y;
        o.z = po.z + ep * qo.z;
        o.w = po.w + ep * qo.w;
        const int lr = r * RR + k;
        if (tt[lr + 1] == tv[k]) {          // rare: duplicate-timestamp run
            int j = row0 + k + 1;
            float tj = tt[lr + 1];
            while (tj == tv[k]) {
                float4 hj = h4[(size_t)j * DV + q];
                o.x += hj.x + eps * fmaxf(hj.x, 0.f);
                o.y += hj.y + eps * fmaxf(hj.y, 0.f);
                o.z += hj.z + eps * fmaxf(hj.z, 0.f);
                o.w += hj.w + eps * fmaxf(hj.w, 0.f);
                ++j;
                if (j >= S) break;
                const int lj = j - c * CH;
                tj = (lj <= CH) ? tt[lj] : t[j];
            }
        }
        out4[(size_t)(row0 + k) * DV + q] = o;
    }
}

extern "C" void kernel_launch(void* const* d_in, const int* in_sizes, int n_in,
                              void* d_out, int out_size, void* d_ws, size_t ws_size,
                              hipStream_t stream) {
    const float* h    = (const float*)d_in[0];
    const float* t    = (const float*)d_in[1];
    const float* eps  = (const float*)d_in[2];
    const float* beta = (const float*)d_in[3];
    float* out = (float*)d_out;

    float4* SP   = (float4*)d_ws;
    float4* SQ   = SP + NC * DV;
    float4* offP = SQ + NC * DV;
    float4* offQ = offP + NC * DV;

    heat_partials<<<dim3(NC, NG), 256, 0, stream>>>(h, t, beta, SP, SQ);
    heat_scan<<<2 * SBP, 256, 0, stream>>>(SP, SQ, offP, offQ);
    heat_out<<<dim3(NC, NG), 256, 0, stream>>>(h, t, eps, beta, offP, offQ, out);
}